// Round 10
// baseline (289.677 us; speedup 1.0000x reference)
//
#include <hip/hip_runtime.h>
#include <math.h>

#define NORB 13
#define NORB2 (NORB * NORB)
#define GB 16                       // b-blocks per strip: 16*104B = 13 full lines
#define ROWF4 (GB * NORB * 2 / 4)   // 104 float4 per strip row
#define NSLOT (NORB * ROWF4)        // 1352 float4 slots per strip
#define CAP 32                      // max entries per (a,b) block list
#define KSPLIT 2                    // k-chunks per (a,group) strip -> 8 WGs/CU

typedef float fx4 __attribute__((ext_vector_type(4)));

// block id per orbital index for L_LIST=[0,0,1,1,2] -> sizes 1,1,3,3,5
__device__ __forceinline__ int blk_of(int p) {
    return p < 1 ? 0 : (p < 2 ? 1 : (p < 5 ? 2 : (p < 8 ? 3 : 4)));
}
__device__ __forceinline__ float ffac(int p, int q) {
    int bp = blk_of(p), bq = blk_of(q);
    return bp < bq ? 1.0f : (bp == bq ? 0.5f : 0.0f);
}

// ---- single-WG CSR build over (a, b-group) bins (validated R6/R7) ----------
__global__ void __launch_bounds__(256)
k_build(const int* __restrict__ edge_index, int* __restrict__ rowptr,
        int* __restrict__ entries, int E, int N, int ngroups) {
    extern __shared__ int sm[];            // cnt[nbins] + cursor[nbins] + part[257]
    int nbins = N * ngroups;
    int* cnt    = sm;
    int* cursor = sm + nbins;
    int* part   = sm + 2 * nbins;
    int tid = threadIdx.x;

    for (int i = tid; i < nbins; i += 256) cnt[i] = 0;
    __syncthreads();

    for (int e = tid; e < E; e += 256) {
        int ie = edge_index[e], je = edge_index[E + e];
        atomicAdd(cnt + ie * ngroups + je / GB, 1);
        atomicAdd(cnt + je * ngroups + ie / GB, 1);
    }
    __syncthreads();

    int per = nbins / 256;
    int base = tid * per;
    int s = 0;
    for (int i = 0; i < per; ++i) s += cnt[base + i];
    part[tid + 1] = s;
    __syncthreads();
    if (tid == 0) {
        part[0] = 0;
        for (int i = 1; i <= 256; ++i) part[i] += part[i - 1];
    }
    __syncthreads();
    int run = part[tid];
    for (int i = 0; i < per; ++i) {
        rowptr[base + i] = run;
        cursor[base + i] = run;
        run += cnt[base + i];
    }
    if (tid == 255) rowptr[nbins] = run;
    __syncthreads();

    for (int e = tid; e < E; e += 256) {
        int ie = edge_index[e], je = edge_index[E + e];
        int pos = atomicAdd(cursor + ie * ngroups + je / GB, 1);
        entries[pos] = (e << 9) | je;                   // forward: phase * hopF
        pos = atomicAdd(cursor + je * ngroups + ie / GB, 1);
        entries[pos] = (e << 9) | 256 | ie;             // reverse: conj * hopF^T
    }
}

// ---- assemble: registers -> global, no LDS strip, no per-k barriers --------
__global__ void __launch_bounds__(256)
k_assemble(const float* __restrict__ hopping,
           const float* __restrict__ onsite,
           const float* __restrict__ kpoints,
           const float* __restrict__ cell_shift,
           const int* __restrict__ rowptr,
           const int* __restrict__ entries,
           float* __restrict__ out,
           int N, int K, int ld, int es, int ngroups) {
    int g  = blockIdx.x % ngroups;
    int a  = (blockIdx.x / ngroups) % N;
    int kc = blockIdx.x / (ngroups * N);
    int kch = (K + KSPLIT - 1) / KSPLIT;
    int k0 = kc * kch, k1 = min(K, k0 + kch);
    int tid = threadIdx.x;
    int b0 = g * GB;
    int nb = min(GB, N - b0);

    // per-b-block compact entry lists (k-independent), built once
    __shared__ int lcnt[GB];
    __shared__ int lent[GB][CAP];
    if (tid < GB) lcnt[tid] = 0;
    __syncthreads();
    int bin = a * ngroups + g;
    int beg = rowptr[bin], end = rowptr[bin + 1];
    for (int it = beg + tid; it < end; it += 256) {
        int ent = entries[it];
        int i = (ent & 255) - b0;
        int pos = atomicAdd(&lcnt[i], 1);
        if (pos < CAP) lent[i][pos] = ent;
    }
    __syncthreads();                      // last barrier in the kernel

    const float* on = onsite + (size_t)a * NORB2;

    // one entry's contribution to element (row p, col q) of block i
    auto contrib = [&](int ent, int p, int q, float kx, float ky, float kz,
                       float& vre, float& vim) {
        int e = ent >> 9;
        int rev = ent & 256;
        float Rx = cell_shift[3 * e], Ry = cell_shift[3 * e + 1], Rz = cell_shift[3 * e + 2];
        float d = kx * Rx + ky * Ry + kz * Rz;
        float s_, c_;
        __sincosf(-6.2831853071795864f * d, &s_, &c_);   // exp(-i*2pi*d)=c+i*s
        float hv = rev ? hopping[(size_t)e * NORB2 + q * NORB + p] * ffac(q, p)
                       : hopping[(size_t)e * NORB2 + p * NORB + q] * ffac(p, q);
        vre += c_ * hv;
        vim += (rev ? -s_ : s_) * hv;
    };

    if (es == 2 && nb == GB) {
        // ---- fast path: per-thread float4 slots, pure store stream ----
        int   sn[6];                      // packed list lengths (n0<<16)|n1
        float so0[6], so1[6];             // onsite (real) per element
#pragma unroll
        for (int u = 0; u < 6; ++u) {
            int s = tid + (u << 8);
            sn[u] = 0; so0[u] = 0.f; so1[u] = 0.f;
            if (s < NSLOT) {
                int row = s / ROWF4;
                int c = s - row * ROWF4;
                int j0 = 2 * c;
                int i0 = j0 / NORB, q0 = j0 - NORB * i0;
                int j1 = j0 + 1;
                int i1 = j1 / NORB, q1 = j1 - NORB * i1;
                sn[u] = (min(lcnt[i0], CAP) << 16) | min(lcnt[i1], CAP);
                if (b0 + i0 == a)
                    so0[u] = on[row * NORB + q0] * ffac(row, q0)
                           + on[q0 * NORB + row] * ffac(q0, row);
                if (b0 + i1 == a)
                    so1[u] = on[row * NORB + q1] * ffac(row, q1)
                           + on[q1 * NORB + row] * ffac(q1, row);
            }
        }

        fx4* o4 = (fx4*)out;
        for (int k = k0; k < k1; ++k) {
            float kx = kpoints[3 * k], ky = kpoints[3 * k + 1], kz = kpoints[3 * k + 2];
#pragma unroll
            for (int u = 0; u < 6; ++u) {
                int s = tid + (u << 8);
                if (s >= NSLOT) break;
                int row = s / ROWF4;
                int c = s - row * ROWF4;
                int j0 = 2 * c;
                int i0 = j0 / NORB, q0 = j0 - NORB * i0;
                int j1 = j0 + 1;
                int i1 = j1 / NORB, q1 = j1 - NORB * i1;
                int n0 = sn[u] >> 16, n1 = sn[u] & 0xffff;
                float re0 = so0[u], im0 = 0.f;
                float re1 = so1[u], im1 = 0.f;
                for (int n = 0; n < n0; ++n)
                    contrib(lent[i0][n], row, q0, kx, ky, kz, re0, im0);
                for (int n = 0; n < n1; ++n)
                    contrib(lent[i1][n], row, q1, kx, ky, kz, re1, im1);
                size_t gc = ((size_t)k * ld + (size_t)a * NORB + row) * ld
                          + (size_t)b0 * NORB;           // complex base, even
                o4[(gc >> 1) + c] = (fx4){re0, im0, re1, im1};
            }
        }
    } else {
        // ---- generic fallback: per complex element ----
        int nelem = NORB * nb * NORB;
        for (int k = k0; k < k1; ++k) {
            float kx = kpoints[3 * k], ky = kpoints[3 * k + 1], kz = kpoints[3 * k + 2];
            for (int idx = tid; idx < nelem; idx += 256) {
                int row = idx / (nb * NORB);
                int rem = idx - row * nb * NORB;
                int i = rem / NORB, q = rem - NORB * i;
                float vre = 0.f, vim = 0.f;
                if (b0 + i == a)
                    vre = on[row * NORB + q] * ffac(row, q)
                        + on[q * NORB + row] * ffac(q, row);
                int n0 = min(lcnt[i], CAP);
                for (int n = 0; n < n0; ++n)
                    contrib(lent[i][n], row, q, kx, ky, kz, vre, vim);
                size_t gc = ((size_t)k * ld + (size_t)a * NORB + row) * ld
                          + (size_t)b0 * NORB + rem;
                if (es == 2) ((float2*)out)[gc] = make_float2(vre, vim);
                else         out[gc] = vre;
            }
        }
    }
}

extern "C" void kernel_launch(void* const* d_in, const int* in_sizes, int n_in,
                              void* d_out, int out_size, void* d_ws, size_t ws_size,
                              hipStream_t stream) {
    const float* hopping    = (const float*)d_in[0];
    const float* onsite     = (const float*)d_in[1];
    const float* kpoints    = (const float*)d_in[2];
    const float* cell_shift = (const float*)d_in[3];
    const int*   edge_index = (const int*)d_in[4];
    float* out = (float*)d_out;

    int E = in_sizes[0] / NORB2;   // 2048
    int N = in_sizes[1] / NORB2;   // 128
    int K = in_sizes[2] / 3;       // 16
    int ld = N * NORB;             // 1664
    int ngroups = (N + GB - 1) / GB;   // 8
    int nbins = N * ngroups;           // 1024

    size_t full = (size_t)K * ld * ld * 2;
    int es = ((size_t)out_size >= full) ? 2 : 1;

    // workspace (ints): rowptr[nbins+1], entries[2E]
    int* rowptr  = (int*)d_ws;
    int* entries = rowptr + nbins + 1;

    size_t build_lds = (size_t)(2 * nbins + 257) * sizeof(int);
    k_build<<<1, 256, build_lds, stream>>>(edge_index, rowptr, entries, E, N, ngroups);

    int nwg = N * ngroups * KSPLIT;             // 2048
    k_assemble<<<nwg, 256, 0, stream>>>(hopping, onsite, kpoints, cell_shift,
                                        rowptr, entries, out, N, K, ld, es, ngroups);
}